// Round 1
// baseline (913.414 us; speedup 1.0000x reference)
//
#include <hip/hip_runtime.h>

#define N_NODES 50000
#define N_EDGES 800000
#define CH 256
#define NUM_GRAPHS 512
#define LEAKY 0.01f
#define LN_EPS 1e-5f

__global__ void zero_ints(int* __restrict__ p, int n) {
    int i = blockIdx.x * blockDim.x + threadIdx.x;
    if (i < n) p[i] = 0;
}

__global__ void count_deg(const int* __restrict__ dst, int* __restrict__ cnt) {
    int e = blockIdx.x * blockDim.x + threadIdx.x;
    if (e < N_EDGES) atomicAdd(&cnt[dst[e]], 1);
}

__global__ void compute_dinv(const int* __restrict__ cnt, float* __restrict__ dinv) {
    int i = blockIdx.x * blockDim.x + threadIdx.x;
    if (i < N_NODES) dinv[i] = rsqrtf(1.0f + (float)cnt[i]);  // +1 = self loop
}

// single-block chunked scan: rowptr[i] = sum cnt[0..i-1], rowptr[N]=total
__global__ void scan_rowptr(const int* __restrict__ cnt, int* __restrict__ rowptr) {
    __shared__ int s[256];
    __shared__ int carry;
    int tid = threadIdx.x;
    if (tid == 0) { carry = 0; rowptr[0] = 0; }
    __syncthreads();
    for (int base = 0; base < N_NODES; base += 256) {
        int i = base + tid;
        int v = (i < N_NODES) ? cnt[i] : 0;
        s[tid] = v;
        __syncthreads();
        #pragma unroll
        for (int off = 1; off < 256; off <<= 1) {
            int t = (tid >= off) ? s[tid - off] : 0;
            __syncthreads();
            s[tid] += t;
            __syncthreads();
        }
        if (i < N_NODES) rowptr[i + 1] = carry + s[tid];
        __syncthreads();
        if (tid == 0) carry += s[255];
        __syncthreads();
    }
}

__global__ void fill_csr(const int* __restrict__ src, const int* __restrict__ dst,
                         const int* __restrict__ rowptr, int* __restrict__ cursor,
                         int* __restrict__ col) {
    int e = blockIdx.x * blockDim.x + threadIdx.x;
    if (e < N_EDGES) {
        int d = dst[e];
        int p = rowptr[d] + atomicAdd(&cursor[d], 1);
        col[p] = src[e];
    }
}

// out[row][col] = (sum_k X[row][k] * W[k][col]) * dinv[row]
// block 256 threads -> 64x64 tile, 4x4 per-thread register sub-tile
__global__ __launch_bounds__(256) void gemm_scale(const float* __restrict__ X,
                                                  const float* __restrict__ W,
                                                  const float* __restrict__ dinv,
                                                  float* __restrict__ out) {
    __shared__ float xsT[16][64];  // [k][row]
    __shared__ float ws[16][64];   // [k][col]
    int row0 = blockIdx.x * 64;
    int col0 = blockIdx.y * 64;
    int tid = threadIdx.x;
    int rr = (tid / 16) * 4;
    int cc = (tid % 16) * 4;
    float acc[4][4] = {};
    for (int k0 = 0; k0 < CH; k0 += 16) {
        {
            int r = tid / 4;          // 0..63
            int kk = (tid % 4) * 4;   // 0,4,8,12
            int row = row0 + r;
            float4 v = make_float4(0.f, 0.f, 0.f, 0.f);
            if (row < N_NODES) v = *(const float4*)&X[row * CH + k0 + kk];
            xsT[kk + 0][r] = v.x; xsT[kk + 1][r] = v.y;
            xsT[kk + 2][r] = v.z; xsT[kk + 3][r] = v.w;
        }
        {
            int kr = tid / 16;        // 0..15
            int c  = (tid % 16) * 4;
            *(float4*)&ws[kr][c] = *(const float4*)&W[(k0 + kr) * CH + col0 + c];
        }
        __syncthreads();
        #pragma unroll
        for (int kk = 0; kk < 16; kk++) {
            float4 a = *(const float4*)&xsT[kk][rr];
            float4 b = *(const float4*)&ws[kk][cc];
            acc[0][0] += a.x * b.x; acc[0][1] += a.x * b.y; acc[0][2] += a.x * b.z; acc[0][3] += a.x * b.w;
            acc[1][0] += a.y * b.x; acc[1][1] += a.y * b.y; acc[1][2] += a.y * b.z; acc[1][3] += a.y * b.w;
            acc[2][0] += a.z * b.x; acc[2][1] += a.z * b.y; acc[2][2] += a.z * b.z; acc[2][3] += a.z * b.w;
            acc[3][0] += a.w * b.x; acc[3][1] += a.w * b.y; acc[3][2] += a.w * b.z; acc[3][3] += a.w * b.w;
        }
        __syncthreads();
    }
    #pragma unroll
    for (int i = 0; i < 4; i++) {
        int row = row0 + rr + i;
        if (row < N_NODES) {
            float s = dinv[row];
            float4 o = make_float4(acc[i][0] * s, acc[i][1] * s, acc[i][2] * s, acc[i][3] * s);
            *(float4*)&out[row * CH + col0 + cc] = o;
        }
    }
}

// per-node gather over in-edges + self loop, then *dinv + bias, LayerNorm, LeakyReLU
__global__ __launch_bounds__(256) void agg_ln(const float* __restrict__ h,
                                              const int* __restrict__ rowptr,
                                              const int* __restrict__ col,
                                              const float* __restrict__ dinv,
                                              const float* __restrict__ bias,
                                              const float* __restrict__ lnw,
                                              const float* __restrict__ lnb,
                                              float* __restrict__ out) {
    int d = blockIdx.x;
    int tid = threadIdx.x;
    float acc = h[d * CH + tid];  // self loop (h already scaled by dinv[src])
    int e0 = rowptr[d], e1 = rowptr[d + 1];
    for (int e = e0; e < e1; e++) {
        int s = col[e];
        acc += h[s * CH + tid];
    }
    acc = acc * dinv[d] + bias[tid];
    __shared__ float red[256], red2[256];
    red[tid] = acc; red2[tid] = acc * acc;
    __syncthreads();
    #pragma unroll
    for (int off = 128; off > 0; off >>= 1) {
        if (tid < off) { red[tid] += red[tid + off]; red2[tid] += red2[tid + off]; }
        __syncthreads();
    }
    float mu  = red[0] * (1.0f / CH);
    float var = red2[0] * (1.0f / CH) - mu * mu;
    float y = (acc - mu) * rsqrtf(var + LN_EPS) * lnw[tid] + lnb[tid];
    out[d * CH + tid] = (y >= 0.f) ? y : LEAKY * y;
}

__global__ __launch_bounds__(256) void pool_mean(const float* __restrict__ feat,
                                                 const int* __restrict__ batch,
                                                 float* __restrict__ out) {
    int g = blockIdx.x;
    int tid = threadIdx.x;
    int lo = 0, hi = N_NODES;
    while (lo < hi) { int mid = (lo + hi) >> 1; if (batch[mid] < g) lo = mid + 1; else hi = mid; }
    int start = lo;
    hi = N_NODES;
    while (lo < hi) { int mid = (lo + hi) >> 1; if (batch[mid] < g + 1) lo = mid + 1; else hi = mid; }
    int end = lo;
    float s = 0.f;
    for (int n = start; n < end; n++) s += feat[n * CH + tid];
    out[g * CH + tid] = (end > start) ? s / (float)(end - start) : 0.f;
}

static inline size_t align256(size_t x) { return (x + 255) & ~(size_t)255; }

extern "C" void kernel_launch(void* const* d_in, const int* in_sizes, int n_in,
                              void* d_out, int out_size, void* d_ws, size_t ws_size,
                              hipStream_t stream) {
    const float* x    = (const float*)d_in[0];
    const int*   edge = (const int*)d_in[1];   // [2, 800000]: src then dst
    const int*   batch= (const int*)d_in[2];
    const float* W1   = (const float*)d_in[3];
    const float* b1   = (const float*)d_in[4];
    const float* ln1w = (const float*)d_in[5];
    const float* ln1b = (const float*)d_in[6];
    const float* W2   = (const float*)d_in[7];
    const float* b2   = (const float*)d_in[8];
    const float* ln2w = (const float*)d_in[9];
    const float* ln2b = (const float*)d_in[10];

    const int* src = edge;
    const int* dst = edge + N_EDGES;

    char* p = (char*)d_ws;
    int* cnt    = (int*)p;  p += align256(N_NODES * 4);
    int* cursor = (int*)p;  p += align256(N_NODES * 4);
    int* rowptr = (int*)p;  p += align256((N_NODES + 1) * 4);
    float* dinv = (float*)p; p += align256(N_NODES * 4);
    int* col    = (int*)p;  p += align256(N_EDGES * 4);
    float* bufA = (float*)p; p += align256((size_t)N_NODES * CH * 4);
    float* bufB = (float*)p;

    zero_ints<<<(N_NODES + 255) / 256, 256, 0, stream>>>(cnt, N_NODES);
    zero_ints<<<(N_NODES + 255) / 256, 256, 0, stream>>>(cursor, N_NODES);
    count_deg<<<(N_EDGES + 255) / 256, 256, 0, stream>>>(dst, cnt);
    compute_dinv<<<(N_NODES + 255) / 256, 256, 0, stream>>>(cnt, dinv);
    scan_rowptr<<<1, 256, 0, stream>>>(cnt, rowptr);
    fill_csr<<<(N_EDGES + 255) / 256, 256, 0, stream>>>(src, dst, rowptr, cursor, col);

    dim3 ggrid((N_NODES + 63) / 64, CH / 64);
    gemm_scale<<<ggrid, 256, 0, stream>>>(x, W1, dinv, bufA);
    agg_ln<<<N_NODES, 256, 0, stream>>>(bufA, rowptr, col, dinv, b1, ln1w, ln1b, bufB);
    gemm_scale<<<ggrid, 256, 0, stream>>>(bufB, W2, dinv, bufA);
    agg_ln<<<N_NODES, 256, 0, stream>>>(bufA, rowptr, col, dinv, b2, ln2w, ln2b, bufB);
    pool_mean<<<NUM_GRAPHS, 256, 0, stream>>>(bufB, batch, (float*)d_out);
}

// Round 3
// 712.583 us; speedup vs baseline: 1.2818x; 1.2818x over previous
//
#include <hip/hip_runtime.h>

#define N_NODES 50000
#define N_EDGES 800000
#define CH 256
#define NUM_GRAPHS 512
#define LEAKY 0.01f
#define LN_EPS 1e-5f
#define NBLK ((N_NODES + 255) / 256)   // 196 (<= 256, fits one scan block)

__global__ void zero_ints(int* __restrict__ p, int n) {
    int i = blockIdx.x * blockDim.x + threadIdx.x;
    if (i < n) p[i] = 0;
}

__global__ void count_deg(const int* __restrict__ dst, int* __restrict__ cnt) {
    int e = blockIdx.x * blockDim.x + threadIdx.x;
    if (e < N_EDGES) atomicAdd(&cnt[dst[e]], 1);
}

// per-block sums of cnt, plus dinv[i] = rsqrt(1+cnt[i]) folded in
__global__ __launch_bounds__(256) void block_reduce(const int* __restrict__ cnt,
                                                    int* __restrict__ bsum,
                                                    float* __restrict__ dinv) {
    __shared__ int s[256];
    int tid = threadIdx.x;
    int i = blockIdx.x * 256 + tid;
    int v = (i < N_NODES) ? cnt[i] : 0;
    if (i < N_NODES) dinv[i] = rsqrtf(1.0f + (float)v);  // +1 = self loop
    s[tid] = v;
    __syncthreads();
    #pragma unroll
    for (int off = 128; off > 0; off >>= 1) {
        if (tid < off) s[tid] += s[tid + off];
        __syncthreads();
    }
    if (tid == 0) bsum[blockIdx.x] = s[0];
}

// single block: exclusive scan of the <=256 block sums (in place)
__global__ __launch_bounds__(256) void scan_bsums(int* __restrict__ bsum) {
    __shared__ int s[256];
    int tid = threadIdx.x;
    int v = (tid < NBLK) ? bsum[tid] : 0;
    s[tid] = v;
    __syncthreads();
    #pragma unroll
    for (int off = 1; off < 256; off <<= 1) {
        int t = (tid >= off) ? s[tid - off] : 0;
        __syncthreads();
        s[tid] += t;
        __syncthreads();
    }
    if (tid < NBLK) bsum[tid] = s[tid] - v;  // exclusive
}

// per-block inclusive scan + block offset -> rowptr[i+1]
__global__ __launch_bounds__(256) void block_scan(const int* __restrict__ cnt,
                                                  const int* __restrict__ bsum,
                                                  int* __restrict__ rowptr) {
    __shared__ int s[256];
    int tid = threadIdx.x;
    int i = blockIdx.x * 256 + tid;
    int v = (i < N_NODES) ? cnt[i] : 0;
    s[tid] = v;
    __syncthreads();
    #pragma unroll
    for (int off = 1; off < 256; off <<= 1) {
        int t = (tid >= off) ? s[tid - off] : 0;
        __syncthreads();
        s[tid] += t;
        __syncthreads();
    }
    if (i < N_NODES) rowptr[i + 1] = bsum[blockIdx.x] + s[tid];
    if (i == 0) rowptr[0] = 0;
}

__global__ void fill_csr(const int* __restrict__ src, const int* __restrict__ dst,
                         const int* __restrict__ rowptr, int* __restrict__ cursor,
                         int* __restrict__ col) {
    int e = blockIdx.x * blockDim.x + threadIdx.x;
    if (e < N_EDGES) {
        int d = dst[e];
        int p = rowptr[d] + atomicAdd(&cursor[d], 1);
        col[p] = src[e];
    }
}

// out[row][col] = (sum_k X[row][k] * W[k][col]) * dinv[row]
// block 256 threads -> 64x64 tile, 4x4 per-thread register sub-tile
__global__ __launch_bounds__(256) void gemm_scale(const float* __restrict__ X,
                                                  const float* __restrict__ W,
                                                  const float* __restrict__ dinv,
                                                  float* __restrict__ out) {
    __shared__ float xsT[16][64];  // [k][row]
    __shared__ float ws[16][64];   // [k][col]
    int row0 = blockIdx.x * 64;
    int col0 = blockIdx.y * 64;
    int tid = threadIdx.x;
    int rr = (tid / 16) * 4;
    int cc = (tid % 16) * 4;
    float acc[4][4] = {};
    for (int k0 = 0; k0 < CH; k0 += 16) {
        {
            int r = tid / 4;          // 0..63
            int kk = (tid % 4) * 4;   // 0,4,8,12
            int row = row0 + r;
            float4 v = make_float4(0.f, 0.f, 0.f, 0.f);
            if (row < N_NODES) v = *(const float4*)&X[row * CH + k0 + kk];
            xsT[kk + 0][r] = v.x; xsT[kk + 1][r] = v.y;
            xsT[kk + 2][r] = v.z; xsT[kk + 3][r] = v.w;
        }
        {
            int kr = tid / 16;        // 0..15
            int c  = (tid % 16) * 4;
            *(float4*)&ws[kr][c] = *(const float4*)&W[(k0 + kr) * CH + col0 + c];
        }
        __syncthreads();
        #pragma unroll
        for (int kk = 0; kk < 16; kk++) {
            float4 a = *(const float4*)&xsT[kk][rr];
            float4 b = *(const float4*)&ws[kk][cc];
            acc[0][0] += a.x * b.x; acc[0][1] += a.x * b.y; acc[0][2] += a.x * b.z; acc[0][3] += a.x * b.w;
            acc[1][0] += a.y * b.x; acc[1][1] += a.y * b.y; acc[1][2] += a.y * b.z; acc[1][3] += a.y * b.w;
            acc[2][0] += a.z * b.x; acc[2][1] += a.z * b.y; acc[2][2] += a.z * b.z; acc[2][3] += a.z * b.w;
            acc[3][0] += a.w * b.x; acc[3][1] += a.w * b.y; acc[3][2] += a.w * b.z; acc[3][3] += a.w * b.w;
        }
        __syncthreads();
    }
    #pragma unroll
    for (int i = 0; i < 4; i++) {
        int row = row0 + rr + i;
        if (row < N_NODES) {
            float s = dinv[row];
            float4 o = make_float4(acc[i][0] * s, acc[i][1] * s, acc[i][2] * s, acc[i][3] * s);
            *(float4*)&out[row * CH + col0 + cc] = o;
        }
    }
}

// per-node gather over in-edges + self loop, then *dinv + bias, LayerNorm, LeakyReLU
__global__ __launch_bounds__(256) void agg_ln(const float* __restrict__ h,
                                              const int* __restrict__ rowptr,
                                              const int* __restrict__ col,
                                              const float* __restrict__ dinv,
                                              const float* __restrict__ bias,
                                              const float* __restrict__ lnw,
                                              const float* __restrict__ lnb,
                                              float* __restrict__ out) {
    int d = blockIdx.x;
    int tid = threadIdx.x;
    float acc = h[d * CH + tid];  // self loop (h already scaled by dinv[src])
    int e0 = rowptr[d], e1 = rowptr[d + 1];
    for (int e = e0; e < e1; e++) {
        int s = col[e];
        acc += h[s * CH + tid];
    }
    acc = acc * dinv[d] + bias[tid];
    __shared__ float red[256], red2[256];
    red[tid] = acc; red2[tid] = acc * acc;
    __syncthreads();
    #pragma unroll
    for (int off = 128; off > 0; off >>= 1) {
        if (tid < off) { red[tid] += red[tid + off]; red2[tid] += red2[tid + off]; }
        __syncthreads();
    }
    float mu  = red[0] * (1.0f / CH);
    float var = red2[0] * (1.0f / CH) - mu * mu;
    float y = (acc - mu) * rsqrtf(var + LN_EPS) * lnw[tid] + lnb[tid];
    out[d * CH + tid] = (y >= 0.f) ? y : LEAKY * y;
}

__global__ __launch_bounds__(256) void pool_mean(const float* __restrict__ feat,
                                                 const int* __restrict__ batch,
                                                 float* __restrict__ out) {
    int g = blockIdx.x;
    int tid = threadIdx.x;
    int lo = 0, hi = N_NODES;
    while (lo < hi) { int mid = (lo + hi) >> 1; if (batch[mid] < g) lo = mid + 1; else hi = mid; }
    int start = lo;
    hi = N_NODES;
    while (lo < hi) { int mid = (lo + hi) >> 1; if (batch[mid] < g + 1) lo = mid + 1; else hi = mid; }
    int end = lo;
    float s = 0.f;
    for (int n = start; n < end; n++) s += feat[n * CH + tid];
    out[g * CH + tid] = (end > start) ? s / (float)(end - start) : 0.f;
}

static inline size_t align256(size_t x) { return (x + 255) & ~(size_t)255; }

extern "C" void kernel_launch(void* const* d_in, const int* in_sizes, int n_in,
                              void* d_out, int out_size, void* d_ws, size_t ws_size,
                              hipStream_t stream) {
    const float* x    = (const float*)d_in[0];
    const int*   edge = (const int*)d_in[1];   // [2, 800000]: src then dst
    const int*   batch= (const int*)d_in[2];
    const float* W1   = (const float*)d_in[3];
    const float* b1   = (const float*)d_in[4];
    const float* ln1w = (const float*)d_in[5];
    const float* ln1b = (const float*)d_in[6];
    const float* W2   = (const float*)d_in[7];
    const float* b2   = (const float*)d_in[8];
    const float* ln2w = (const float*)d_in[9];
    const float* ln2b = (const float*)d_in[10];

    const int* src = edge;
    const int* dst = edge + N_EDGES;

    char* p = (char*)d_ws;
    int* cnt    = (int*)p;  p += align256(N_NODES * 4);
    int* cursor = (int*)p;  p += align256(N_NODES * 4);
    int* rowptr = (int*)p;  p += align256((N_NODES + 1) * 4);
    int* bsum   = (int*)p;  p += align256(NBLK * 4);
    float* dinv = (float*)p; p += align256(N_NODES * 4);
    int* col    = (int*)p;  p += align256(N_EDGES * 4);
    float* bufA = (float*)p; p += align256((size_t)N_NODES * CH * 4);
    float* bufB = (float*)p;

    // zero the FULL contiguous cnt..cursor span INCLUDING the align256 pad
    // (round-2 bug: zeroing 2*N_NODES ints left cursor's tail 48 ints stale
    //  because cnt's region is padded to 50048 ints -> OOB col[] writes -> abort)
    const int ztotal = (int)(align256(N_NODES * 4) / 4 + N_NODES);  // 100048
    zero_ints<<<(ztotal + 255) / 256, 256, 0, stream>>>(cnt, ztotal);
    count_deg<<<(N_EDGES + 255) / 256, 256, 0, stream>>>(dst, cnt);
    block_reduce<<<NBLK, 256, 0, stream>>>(cnt, bsum, dinv);
    scan_bsums<<<1, 256, 0, stream>>>(bsum);
    block_scan<<<NBLK, 256, 0, stream>>>(cnt, bsum, rowptr);
    fill_csr<<<(N_EDGES + 255) / 256, 256, 0, stream>>>(src, dst, rowptr, cursor, col);

    dim3 ggrid((N_NODES + 63) / 64, CH / 64);
    gemm_scale<<<ggrid, 256, 0, stream>>>(x, W1, dinv, bufA);
    agg_ln<<<N_NODES, 256, 0, stream>>>(bufA, rowptr, col, dinv, b1, ln1w, ln1b, bufB);
    gemm_scale<<<ggrid, 256, 0, stream>>>(bufB, W2, dinv, bufA);
    agg_ln<<<N_NODES, 256, 0, stream>>>(bufA, rowptr, col, dinv, b2, ln2w, ln2b, bufB);
    pool_mean<<<NUM_GRAPHS, 256, 0, stream>>>(bufB, batch, (float*)d_out);
}

// Round 4
// 389.497 us; speedup vs baseline: 2.3451x; 1.8295x over previous
//
#include <hip/hip_runtime.h>

#define N_NODES 50000
#define N_EDGES 800000
#define CH 256
#define NUM_GRAPHS 512
#define LEAKY 0.01f
#define LN_EPS 1e-5f
#define NBLK ((N_NODES + 255) / 256)   // 196

typedef __attribute__((ext_vector_type(4))) float f32x4;
typedef __attribute__((ext_vector_type(8))) short bf16x8;

__device__ __forceinline__ float b2f(unsigned short u) {
    union { unsigned int i; float f; } x; x.i = ((unsigned int)u) << 16; return x.f;
}
__device__ __forceinline__ unsigned short f2b(float f) {  // round-to-nearest-even
    union { float f; unsigned int i; } x; x.f = f;
    unsigned int r = x.i + 0x7fffu + ((x.i >> 16) & 1u);
    return (unsigned short)(r >> 16);
}

__global__ void zero_ints(int* __restrict__ p, int n) {
    int i = blockIdx.x * blockDim.x + threadIdx.x;
    if (i < n) p[i] = 0;
}

__global__ void count_deg(const int* __restrict__ dst, int* __restrict__ cnt) {
    int e = blockIdx.x * blockDim.x + threadIdx.x;
    if (e < N_EDGES) atomicAdd(&cnt[dst[e]], 1);
}

__global__ __launch_bounds__(256) void block_reduce(const int* __restrict__ cnt,
                                                    int* __restrict__ bsum,
                                                    float* __restrict__ dinv) {
    __shared__ int s[256];
    int tid = threadIdx.x;
    int i = blockIdx.x * 256 + tid;
    int v = (i < N_NODES) ? cnt[i] : 0;
    if (i < N_NODES) dinv[i] = rsqrtf(1.0f + (float)v);
    s[tid] = v;
    __syncthreads();
    #pragma unroll
    for (int off = 128; off > 0; off >>= 1) {
        if (tid < off) s[tid] += s[tid + off];
        __syncthreads();
    }
    if (tid == 0) bsum[blockIdx.x] = s[0];
}

__global__ __launch_bounds__(256) void scan_bsums(int* __restrict__ bsum) {
    __shared__ int s[256];
    int tid = threadIdx.x;
    int v = (tid < NBLK) ? bsum[tid] : 0;
    s[tid] = v;
    __syncthreads();
    #pragma unroll
    for (int off = 1; off < 256; off <<= 1) {
        int t = (tid >= off) ? s[tid - off] : 0;
        __syncthreads();
        s[tid] += t;
        __syncthreads();
    }
    if (tid < NBLK) bsum[tid] = s[tid] - v;
}

__global__ __launch_bounds__(256) void block_scan(const int* __restrict__ cnt,
                                                  const int* __restrict__ bsum,
                                                  int* __restrict__ rowptr) {
    __shared__ int s[256];
    int tid = threadIdx.x;
    int i = blockIdx.x * 256 + tid;
    int v = (i < N_NODES) ? cnt[i] : 0;
    s[tid] = v;
    __syncthreads();
    #pragma unroll
    for (int off = 1; off < 256; off <<= 1) {
        int t = (tid >= off) ? s[tid - off] : 0;
        __syncthreads();
        s[tid] += t;
        __syncthreads();
    }
    if (i < N_NODES) rowptr[i + 1] = bsum[blockIdx.x] + s[tid];
    if (i == 0) rowptr[0] = 0;
}

__global__ void fill_csr(const int* __restrict__ src, const int* __restrict__ dst,
                         const int* __restrict__ rowptr, int* __restrict__ cursor,
                         int* __restrict__ col) {
    int e = blockIdx.x * blockDim.x + threadIdx.x;
    if (e < N_EDGES) {
        int d = dst[e];
        int p = rowptr[d] + atomicAdd(&cursor[d], 1);
        col[p] = src[e];
    }
}

// f32 -> bf16 cast, vectorized (n4 = count of float4 groups)
__global__ void cast_f32_bf16(const float* __restrict__ in, unsigned short* __restrict__ out, int n4) {
    int i = blockIdx.x * blockDim.x + threadIdx.x;
    if (i < n4) {
        float4 v = ((const float4*)in)[i];
        ushort4 o = make_ushort4(f2b(v.x), f2b(v.y), f2b(v.z), f2b(v.w));
        ((ushort4*)out)[i] = o;
    }
}

// W[256][256] f32 -> WT[256][256] bf16 with WT[n][k] = W[k][n]; grid 256, block 256
__global__ void transpose_w(const float* __restrict__ W, unsigned short* __restrict__ WT) {
    int k = blockIdx.x;
    int n = threadIdx.x;
    WT[n * CH + k] = f2b(W[k * CH + n]);
}

// ---------------- MFMA GEMM: out[m][n] = dinv[m] * sum_k A[m][k]*W[k][n] (bf16 in/out, f32 accum)
// A: [M][256] bf16 row-major; BT: [256][256] bf16, BT[n][k] = W[k][n]
#define BM 128
#define BN 128
#define BK 64
// swizzled LDS byte offset for [row][64 bf16] tiles (T2: spread 8 rows over 8 16B slots)
#define SWZ(row, kb) (((row) * 128 + (kb) * 16) ^ (((row) & 7) << 4))

__global__ __launch_bounds__(256) void gemm_bf16(const unsigned short* __restrict__ A,
                                                 const unsigned short* __restrict__ BT,
                                                 const float* __restrict__ dinv,
                                                 unsigned short* __restrict__ out) {
    __shared__ unsigned short As[BM * BK];
    __shared__ unsigned short Bs[BN * BK];
    const int row0 = blockIdx.x * BM;
    const int col0 = blockIdx.y * BN;
    const int tid = threadIdx.x;
    const int w = tid >> 6, l = tid & 63;
    const int wr = w >> 1, wc = w & 1;    // 2x2 wave grid, each wave 64x64 output
    const int lr = l & 15, lg = l >> 4;

    f32x4 acc[4][4] = {};  // [fm][fn], each f32x4 = 4 rows of a 16x16 frag

    for (int k0 = 0; k0 < CH; k0 += BK) {
        #pragma unroll
        for (int it = 0; it < 4; it++) {
            int cidx = it * 256 + tid;         // 0..1023 : 128 rows x 8 chunks(16B)
            int r = cidx >> 3, kb = cidx & 7;
            int grow = row0 + r;
            uint4 va = make_uint4(0u, 0u, 0u, 0u);
            if (grow < N_NODES) va = *(const uint4*)&A[(size_t)grow * CH + k0 + kb * 8];
            *(uint4*)((char*)As + SWZ(r, kb)) = va;
            uint4 vb = *(const uint4*)&BT[(size_t)(col0 + r) * CH + k0 + kb * 8];
            *(uint4*)((char*)Bs + SWZ(r, kb)) = vb;
        }
        __syncthreads();
        #pragma unroll
        for (int ks = 0; ks < 2; ks++) {
            bf16x8 af[4], bfr[4];
            #pragma unroll
            for (int fm = 0; fm < 4; fm++) {
                int r = wr * 64 + fm * 16 + lr;
                af[fm] = *(const bf16x8*)((const char*)As + SWZ(r, ks * 4 + lg));
            }
            #pragma unroll
            for (int fn = 0; fn < 4; fn++) {
                int r = wc * 64 + fn * 16 + lr;
                bfr[fn] = *(const bf16x8*)((const char*)Bs + SWZ(r, ks * 4 + lg));
            }
            #pragma unroll
            for (int fm = 0; fm < 4; fm++)
                #pragma unroll
                for (int fn = 0; fn < 4; fn++)
                    acc[fm][fn] = __builtin_amdgcn_mfma_f32_16x16x32_bf16(af[fm], bfr[fn], acc[fm][fn], 0, 0, 0);
        }
        __syncthreads();
    }
    // epilogue: D row = (l>>4)*4 + reg, col = l&15  (m89-verified layout)
    #pragma unroll
    for (int fm = 0; fm < 4; fm++) {
        #pragma unroll
        for (int r = 0; r < 4; r++) {
            int grow = row0 + wr * 64 + fm * 16 + lg * 4 + r;
            if (grow < N_NODES) {
                float s = dinv[grow];
                #pragma unroll
                for (int fn = 0; fn < 4; fn++) {
                    int gcol = col0 + wc * 64 + fn * 16 + lr;
                    out[(size_t)grow * CH + gcol] = f2b(acc[fm][fn][r] * s);
                }
            }
        }
    }
}

// ---------------- aggregation + LN + LeakyReLU, one WAVE per node, bf16 in/out
__global__ __launch_bounds__(256) void agg_ln_bf16(const unsigned short* __restrict__ h,
                                                   const int* __restrict__ rowptr,
                                                   const int* __restrict__ col,
                                                   const float* __restrict__ dinv,
                                                   const float* __restrict__ bias,
                                                   const float* __restrict__ lnw,
                                                   const float* __restrict__ lnb,
                                                   unsigned short* __restrict__ out) {
    const int w = threadIdx.x >> 6, lane = threadIdx.x & 63;
    const int d = blockIdx.x * 4 + w;
    if (d >= N_NODES) return;
    const int c4 = lane * 4;

    ushort4 v = *(const ushort4*)&h[(size_t)d * CH + c4];  // self loop
    float a0 = b2f(v.x), a1 = b2f(v.y), a2 = b2f(v.z), a3 = b2f(v.w);

    const int e0 = rowptr[d], e1 = rowptr[d + 1];
    for (int e = e0; e < e1; e++) {
        int s = col[e];
        ushort4 u = *(const ushort4*)&h[(size_t)s * CH + c4];
        a0 += b2f(u.x); a1 += b2f(u.y); a2 += b2f(u.z); a3 += b2f(u.w);
    }
    const float di = dinv[d];
    float4 bb = *(const float4*)&bias[c4];
    a0 = a0 * di + bb.x; a1 = a1 * di + bb.y; a2 = a2 * di + bb.z; a3 = a3 * di + bb.w;

    float s1 = a0 + a1 + a2 + a3;
    float s2 = a0 * a0 + a1 * a1 + a2 * a2 + a3 * a3;
    #pragma unroll
    for (int off = 32; off > 0; off >>= 1) {
        s1 += __shfl_xor(s1, off);
        s2 += __shfl_xor(s2, off);
    }
    const float mu = s1 * (1.0f / CH);
    const float rstd = rsqrtf(s2 * (1.0f / CH) - mu * mu + LN_EPS);
    float4 wv = *(const float4*)&lnw[c4];
    float4 bv = *(const float4*)&lnb[c4];
    float y0 = (a0 - mu) * rstd * wv.x + bv.x;
    float y1 = (a1 - mu) * rstd * wv.y + bv.y;
    float y2 = (a2 - mu) * rstd * wv.z + bv.z;
    float y3 = (a3 - mu) * rstd * wv.w + bv.w;
    y0 = (y0 >= 0.f) ? y0 : LEAKY * y0;
    y1 = (y1 >= 0.f) ? y1 : LEAKY * y1;
    y2 = (y2 >= 0.f) ? y2 : LEAKY * y2;
    y3 = (y3 >= 0.f) ? y3 : LEAKY * y3;
    *(ushort4*)&out[(size_t)d * CH + c4] = make_ushort4(f2b(y0), f2b(y1), f2b(y2), f2b(y3));
}

// one wave per graph; lane owns 4 channels
__global__ __launch_bounds__(64) void pool_mean_bf16(const unsigned short* __restrict__ feat,
                                                     const int* __restrict__ batch,
                                                     float* __restrict__ out) {
    const int g = blockIdx.x;
    const int lane = threadIdx.x;
    int lo = 0, hi = N_NODES;
    while (lo < hi) { int mid = (lo + hi) >> 1; if (batch[mid] < g) lo = mid + 1; else hi = mid; }
    const int start = lo;
    hi = N_NODES;
    while (lo < hi) { int mid = (lo + hi) >> 1; if (batch[mid] < g + 1) lo = mid + 1; else hi = mid; }
    const int end = lo;
    float a0 = 0.f, a1 = 0.f, a2 = 0.f, a3 = 0.f;
    for (int n = start; n < end; n++) {
        ushort4 u = *(const ushort4*)&feat[(size_t)n * CH + lane * 4];
        a0 += b2f(u.x); a1 += b2f(u.y); a2 += b2f(u.z); a3 += b2f(u.w);
    }
    const float inv = (end > start) ? 1.0f / (float)(end - start) : 0.0f;
    float4 o = make_float4(a0 * inv, a1 * inv, a2 * inv, a3 * inv);
    *(float4*)&out[(size_t)g * CH + lane * 4] = o;
}

static inline size_t align256(size_t x) { return (x + 255) & ~(size_t)255; }

extern "C" void kernel_launch(void* const* d_in, const int* in_sizes, int n_in,
                              void* d_out, int out_size, void* d_ws, size_t ws_size,
                              hipStream_t stream) {
    const float* x    = (const float*)d_in[0];
    const int*   edge = (const int*)d_in[1];
    const int*   batch= (const int*)d_in[2];
    const float* W1   = (const float*)d_in[3];
    const float* b1   = (const float*)d_in[4];
    const float* ln1w = (const float*)d_in[5];
    const float* ln1b = (const float*)d_in[6];
    const float* W2   = (const float*)d_in[7];
    const float* b2   = (const float*)d_in[8];
    const float* ln2w = (const float*)d_in[9];
    const float* ln2b = (const float*)d_in[10];

    const int* src = edge;
    const int* dst = edge + N_EDGES;

    char* p = (char*)d_ws;
    int* cnt    = (int*)p;  p += align256(N_NODES * 4);
    int* cursor = (int*)p;  p += align256(N_NODES * 4);
    int* rowptr = (int*)p;  p += align256((N_NODES + 1) * 4);
    int* bsum   = (int*)p;  p += align256(NBLK * 4);
    float* dinv = (float*)p; p += align256(N_NODES * 4);
    int* col    = (int*)p;  p += align256(N_EDGES * 4);
    unsigned short* xb  = (unsigned short*)p; p += align256((size_t)N_NODES * CH * 2);
    unsigned short* wt1 = (unsigned short*)p; p += align256(CH * CH * 2);
    unsigned short* wt2 = (unsigned short*)p; p += align256(CH * CH * 2);
    unsigned short* bufA = (unsigned short*)p; p += align256((size_t)N_NODES * CH * 2);
    unsigned short* bufB = (unsigned short*)p;

    // zero cnt..cursor span INCLUDING alignment pad (round-2 lesson)
    const int ztotal = (int)(align256(N_NODES * 4) / 4 + N_NODES);
    zero_ints<<<(ztotal + 255) / 256, 256, 0, stream>>>(cnt, ztotal);
    count_deg<<<(N_EDGES + 255) / 256, 256, 0, stream>>>(dst, cnt);
    block_reduce<<<NBLK, 256, 0, stream>>>(cnt, bsum, dinv);
    scan_bsums<<<1, 256, 0, stream>>>(bsum);
    block_scan<<<NBLK, 256, 0, stream>>>(cnt, bsum, rowptr);
    fill_csr<<<(N_EDGES + 255) / 256, 256, 0, stream>>>(src, dst, rowptr, cursor, col);

    cast_f32_bf16<<<(N_NODES * CH / 4 + 255) / 256, 256, 0, stream>>>(x, xb, N_NODES * CH / 4);
    transpose_w<<<CH, CH, 0, stream>>>(W1, wt1);
    transpose_w<<<CH, CH, 0, stream>>>(W2, wt2);

    dim3 ggrid((N_NODES + BM - 1) / BM, CH / BN);
    gemm_bf16<<<ggrid, 256, 0, stream>>>(xb, wt1, dinv, bufA);
    agg_ln_bf16<<<(N_NODES + 3) / 4, 256, 0, stream>>>(bufA, rowptr, col, dinv, b1, ln1w, ln1b, bufB);
    gemm_bf16<<<ggrid, 256, 0, stream>>>(bufB, wt2, dinv, bufA);
    agg_ln_bf16<<<(N_NODES + 3) / 4, 256, 0, stream>>>(bufA, rowptr, col, dinv, b2, ln2w, ln2b, bufB);
    pool_mean_bf16<<<NUM_GRAPHS, 64, 0, stream>>>(bufB, batch, (float*)d_out);
}

// Round 5
// 299.314 us; speedup vs baseline: 3.0517x; 1.3013x over previous
//
#include <hip/hip_runtime.h>

#define N_NODES 50000
#define N_EDGES 800000
#define CH 256
#define NUM_GRAPHS 512
#define LEAKY 0.01f
#define LN_EPS 1e-5f
#define NBLK ((N_NODES + 255) / 256)   // 196

typedef __attribute__((ext_vector_type(4))) float f32x4;
typedef __attribute__((ext_vector_type(8))) short bf16x8;

__device__ __forceinline__ float b2f(unsigned short u) {
    union { unsigned int i; float f; } x; x.i = ((unsigned int)u) << 16; return x.f;
}
__device__ __forceinline__ unsigned short f2b(float f) {  // round-to-nearest-even
    union { float f; unsigned int i; } x; x.f = f;
    unsigned int r = x.i + 0x7fffu + ((x.i >> 16) & 1u);
    return (unsigned short)(r >> 16);
}

__global__ void zero_ints(int* __restrict__ p, int n) {
    int i = blockIdx.x * blockDim.x + threadIdx.x;
    if (i < n) p[i] = 0;
}

__global__ void count_deg(const int* __restrict__ dst, int* __restrict__ cnt) {
    int e = blockIdx.x * blockDim.x + threadIdx.x;
    if (e < N_EDGES) atomicAdd(&cnt[dst[e]], 1);
}

__global__ __launch_bounds__(256) void block_reduce(const int* __restrict__ cnt,
                                                    int* __restrict__ bsum,
                                                    float* __restrict__ dinv) {
    __shared__ int s[256];
    int tid = threadIdx.x;
    int i = blockIdx.x * 256 + tid;
    int v = (i < N_NODES) ? cnt[i] : 0;
    if (i < N_NODES) dinv[i] = rsqrtf(1.0f + (float)v);
    s[tid] = v;
    __syncthreads();
    #pragma unroll
    for (int off = 128; off > 0; off >>= 1) {
        if (tid < off) s[tid] += s[tid + off];
        __syncthreads();
    }
    if (tid == 0) bsum[blockIdx.x] = s[0];
}

__global__ __launch_bounds__(256) void scan_bsums(int* __restrict__ bsum) {
    __shared__ int s[256];
    int tid = threadIdx.x;
    int v = (tid < NBLK) ? bsum[tid] : 0;
    s[tid] = v;
    __syncthreads();
    #pragma unroll
    for (int off = 1; off < 256; off <<= 1) {
        int t = (tid >= off) ? s[tid - off] : 0;
        __syncthreads();
        s[tid] += t;
        __syncthreads();
    }
    if (tid < NBLK) bsum[tid] = s[tid] - v;
}

__global__ __launch_bounds__(256) void block_scan(const int* __restrict__ cnt,
                                                  const int* __restrict__ bsum,
                                                  int* __restrict__ rowptr) {
    __shared__ int s[256];
    int tid = threadIdx.x;
    int i = blockIdx.x * 256 + tid;
    int v = (i < N_NODES) ? cnt[i] : 0;
    s[tid] = v;
    __syncthreads();
    #pragma unroll
    for (int off = 1; off < 256; off <<= 1) {
        int t = (tid >= off) ? s[tid - off] : 0;
        __syncthreads();
        s[tid] += t;
        __syncthreads();
    }
    if (i < N_NODES) rowptr[i + 1] = bsum[blockIdx.x] + s[tid];
    if (i == 0) rowptr[0] = 0;
}

__global__ void fill_csr(const int* __restrict__ src, const int* __restrict__ dst,
                         const int* __restrict__ rowptr, int* __restrict__ cursor,
                         int* __restrict__ col) {
    int e = blockIdx.x * blockDim.x + threadIdx.x;
    if (e < N_EDGES) {
        int d = dst[e];
        int p = rowptr[d] + atomicAdd(&cursor[d], 1);
        col[p] = src[e];
    }
}

__global__ void cast_f32_bf16(const float* __restrict__ in, unsigned short* __restrict__ out, int n4) {
    int i = blockIdx.x * blockDim.x + threadIdx.x;
    if (i < n4) {
        float4 v = ((const float4*)in)[i];
        ushort4 o = make_ushort4(f2b(v.x), f2b(v.y), f2b(v.z), f2b(v.w));
        ((ushort4*)out)[i] = o;
    }
}

__global__ void transpose_w(const float* __restrict__ W, unsigned short* __restrict__ WT) {
    int k = blockIdx.x;
    int n = threadIdx.x;
    WT[n * CH + k] = f2b(W[k * CH + n]);
}

// ---------------- MFMA GEMM (unchanged from round 4)
#define BM 128
#define BN 128
#define BK 64
#define SWZ(row, kb) (((row) * 128 + (kb) * 16) ^ (((row) & 7) << 4))

__global__ __launch_bounds__(256) void gemm_bf16(const unsigned short* __restrict__ A,
                                                 const unsigned short* __restrict__ BT,
                                                 const float* __restrict__ dinv,
                                                 unsigned short* __restrict__ out) {
    __shared__ unsigned short As[BM * BK];
    __shared__ unsigned short Bs[BN * BK];
    const int row0 = blockIdx.x * BM;
    const int col0 = blockIdx.y * BN;
    const int tid = threadIdx.x;
    const int w = tid >> 6, l = tid & 63;
    const int wr = w >> 1, wc = w & 1;
    const int lr = l & 15, lg = l >> 4;

    f32x4 acc[4][4] = {};

    for (int k0 = 0; k0 < CH; k0 += BK) {
        #pragma unroll
        for (int it = 0; it < 4; it++) {
            int cidx = it * 256 + tid;
            int r = cidx >> 3, kb = cidx & 7;
            int grow = row0 + r;
            uint4 va = make_uint4(0u, 0u, 0u, 0u);
            if (grow < N_NODES) va = *(const uint4*)&A[(size_t)grow * CH + k0 + kb * 8];
            *(uint4*)((char*)As + SWZ(r, kb)) = va;
            uint4 vb = *(const uint4*)&BT[(size_t)(col0 + r) * CH + k0 + kb * 8];
            *(uint4*)((char*)Bs + SWZ(r, kb)) = vb;
        }
        __syncthreads();
        #pragma unroll
        for (int ks = 0; ks < 2; ks++) {
            bf16x8 af[4], bfr[4];
            #pragma unroll
            for (int fm = 0; fm < 4; fm++) {
                int r = wr * 64 + fm * 16 + lr;
                af[fm] = *(const bf16x8*)((const char*)As + SWZ(r, ks * 4 + lg));
            }
            #pragma unroll
            for (int fn = 0; fn < 4; fn++) {
                int r = wc * 64 + fn * 16 + lr;
                bfr[fn] = *(const bf16x8*)((const char*)Bs + SWZ(r, ks * 4 + lg));
            }
            #pragma unroll
            for (int fm = 0; fm < 4; fm++)
                #pragma unroll
                for (int fn = 0; fn < 4; fn++)
                    acc[fm][fn] = __builtin_amdgcn_mfma_f32_16x16x32_bf16(af[fm], bfr[fn], acc[fm][fn], 0, 0, 0);
        }
        __syncthreads();
    }
    #pragma unroll
    for (int fm = 0; fm < 4; fm++) {
        #pragma unroll
        for (int r = 0; r < 4; r++) {
            int grow = row0 + wr * 64 + fm * 16 + lg * 4 + r;
            if (grow < N_NODES) {
                float s = dinv[grow];
                #pragma unroll
                for (int fn = 0; fn < 4; fn++) {
                    int gcol = col0 + wc * 64 + fn * 16 + lr;
                    out[(size_t)grow * CH + gcol] = f2b(acc[fm][fn][r] * s);
                }
            }
        }
    }
}

// ---------------- aggregation + LN + LeakyReLU, one WAVE per node
// wave-cooperative col fetch (__shfl broadcast) + 4x unrolled gather for MLP
__global__ __launch_bounds__(256) void agg_ln_bf16(const unsigned short* __restrict__ h,
                                                   const int* __restrict__ rowptr,
                                                   const int* __restrict__ col,
                                                   const float* __restrict__ dinv,
                                                   const float* __restrict__ bias,
                                                   const float* __restrict__ lnw,
                                                   const float* __restrict__ lnb,
                                                   unsigned short* __restrict__ out) {
    const int w = threadIdx.x >> 6, lane = threadIdx.x & 63;
    const int d = blockIdx.x * 4 + w;
    if (d >= N_NODES) return;   // wave-uniform exit
    const int c4 = lane * 4;

    ushort4 v = *(const ushort4*)&h[(size_t)d * CH + c4];  // self loop
    float a0 = b2f(v.x), a1 = b2f(v.y), a2 = b2f(v.z), a3 = b2f(v.w);

    const int e0 = rowptr[d], e1 = rowptr[d + 1];
    for (int base = e0; base < e1; base += 64) {
        int nch = e1 - base; if (nch > 64) nch = 64;
        int cidx = (lane < nch) ? col[base + lane] : 0;  // one coalesced load / 64 edges
        int j = 0;
        for (; j + 4 <= nch; j += 4) {
            int s0 = __shfl(cidx, j);
            int s1 = __shfl(cidx, j + 1);
            int s2 = __shfl(cidx, j + 2);
            int s3 = __shfl(cidx, j + 3);
            ushort4 u0 = *(const ushort4*)&h[(size_t)s0 * CH + c4];
            ushort4 u1 = *(const ushort4*)&h[(size_t)s1 * CH + c4];
            ushort4 u2 = *(const ushort4*)&h[(size_t)s2 * CH + c4];
            ushort4 u3 = *(const ushort4*)&h[(size_t)s3 * CH + c4];
            a0 += b2f(u0.x) + b2f(u1.x) + b2f(u2.x) + b2f(u3.x);
            a1 += b2f(u0.y) + b2f(u1.y) + b2f(u2.y) + b2f(u3.y);
            a2 += b2f(u0.z) + b2f(u1.z) + b2f(u2.z) + b2f(u3.z);
            a3 += b2f(u0.w) + b2f(u1.w) + b2f(u2.w) + b2f(u3.w);
        }
        for (; j < nch; j++) {
            int s = __shfl(cidx, j);
            ushort4 u = *(const ushort4*)&h[(size_t)s * CH + c4];
            a0 += b2f(u.x); a1 += b2f(u.y); a2 += b2f(u.z); a3 += b2f(u.w);
        }
    }
    const float di = dinv[d];
    float4 bb = *(const float4*)&bias[c4];
    a0 = a0 * di + bb.x; a1 = a1 * di + bb.y; a2 = a2 * di + bb.z; a3 = a3 * di + bb.w;

    float s1 = a0 + a1 + a2 + a3;
    float s2 = a0 * a0 + a1 * a1 + a2 * a2 + a3 * a3;
    #pragma unroll
    for (int off = 32; off > 0; off >>= 1) {
        s1 += __shfl_xor(s1, off);
        s2 += __shfl_xor(s2, off);
    }
    const float mu = s1 * (1.0f / CH);
    const float rstd = rsqrtf(s2 * (1.0f / CH) - mu * mu + LN_EPS);
    float4 wv = *(const float4*)&lnw[c4];
    float4 bv = *(const float4*)&lnb[c4];
    float y0 = (a0 - mu) * rstd * wv.x + bv.x;
    float y1 = (a1 - mu) * rstd * wv.y + bv.y;
    float y2 = (a2 - mu) * rstd * wv.z + bv.z;
    float y3 = (a3 - mu) * rstd * wv.w + bv.w;
    y0 = (y0 >= 0.f) ? y0 : LEAKY * y0;
    y1 = (y1 >= 0.f) ? y1 : LEAKY * y1;
    y2 = (y2 >= 0.f) ? y2 : LEAKY * y2;
    y3 = (y3 >= 0.f) ? y3 : LEAKY * y3;
    *(ushort4*)&out[(size_t)d * CH + c4] = make_ushort4(f2b(y0), f2b(y1), f2b(y2), f2b(y3));
}

// 4 waves per graph, node range split across waves, LDS cross-wave reduce
__global__ __launch_bounds__(256) void pool_mean_bf16(const unsigned short* __restrict__ feat,
                                                      const int* __restrict__ batch,
                                                      float* __restrict__ out) {
    const int g = blockIdx.x;
    const int w = threadIdx.x >> 6, lane = threadIdx.x & 63;
    int lo = 0, hi = N_NODES;
    while (lo < hi) { int mid = (lo + hi) >> 1; if (batch[mid] < g) lo = mid + 1; else hi = mid; }
    const int start = lo;
    hi = N_NODES;
    while (lo < hi) { int mid = (lo + hi) >> 1; if (batch[mid] < g + 1) lo = mid + 1; else hi = mid; }
    const int end = lo;

    float a0 = 0.f, a1 = 0.f, a2 = 0.f, a3 = 0.f;
    for (int n = start + w; n < end; n += 4) {
        ushort4 u = *(const ushort4*)&feat[(size_t)n * CH + lane * 4];
        a0 += b2f(u.x); a1 += b2f(u.y); a2 += b2f(u.z); a3 += b2f(u.w);
    }
    __shared__ float4 red[4][64];
    red[w][lane] = make_float4(a0, a1, a2, a3);
    __syncthreads();
    if (w == 0) {
        float4 t0 = red[0][lane], t1 = red[1][lane], t2 = red[2][lane], t3 = red[3][lane];
        const float inv = (end > start) ? 1.0f / (float)(end - start) : 0.0f;
        float4 o = make_float4((t0.x + t1.x + t2.x + t3.x) * inv,
                               (t0.y + t1.y + t2.y + t3.y) * inv,
                               (t0.z + t1.z + t2.z + t3.z) * inv,
                               (t0.w + t1.w + t2.w + t3.w) * inv);
        *(float4*)&out[(size_t)g * CH + lane * 4] = o;
    }
}

static inline size_t align256(size_t x) { return (x + 255) & ~(size_t)255; }

extern "C" void kernel_launch(void* const* d_in, const int* in_sizes, int n_in,
                              void* d_out, int out_size, void* d_ws, size_t ws_size,
                              hipStream_t stream) {
    const float* x    = (const float*)d_in[0];
    const int*   edge = (const int*)d_in[1];
    const int*   batch= (const int*)d_in[2];
    const float* W1   = (const float*)d_in[3];
    const float* b1   = (const float*)d_in[4];
    const float* ln1w = (const float*)d_in[5];
    const float* ln1b = (const float*)d_in[6];
    const float* W2   = (const float*)d_in[7];
    const float* b2   = (const float*)d_in[8];
    const float* ln2w = (const float*)d_in[9];
    const float* ln2b = (const float*)d_in[10];

    const int* src = edge;
    const int* dst = edge + N_EDGES;

    char* p = (char*)d_ws;
    int* cnt    = (int*)p;  p += align256(N_NODES * 4);
    int* cursor = (int*)p;  p += align256(N_NODES * 4);
    int* rowptr = (int*)p;  p += align256((N_NODES + 1) * 4);
    int* bsum   = (int*)p;  p += align256(NBLK * 4);
    float* dinv = (float*)p; p += align256(N_NODES * 4);
    int* col    = (int*)p;  p += align256(N_EDGES * 4);
    unsigned short* xb  = (unsigned short*)p; p += align256((size_t)N_NODES * CH * 2);
    unsigned short* wt1 = (unsigned short*)p; p += align256(CH * CH * 2);
    unsigned short* wt2 = (unsigned short*)p; p += align256(CH * CH * 2);
    unsigned short* bufA = (unsigned short*)p; p += align256((size_t)N_NODES * CH * 2);
    unsigned short* bufB = (unsigned short*)p;

    const int ztotal = (int)(align256(N_NODES * 4) / 4 + N_NODES);
    zero_ints<<<(ztotal + 255) / 256, 256, 0, stream>>>(cnt, ztotal);
    count_deg<<<(N_EDGES + 255) / 256, 256, 0, stream>>>(dst, cnt);
    block_reduce<<<NBLK, 256, 0, stream>>>(cnt, bsum, dinv);
    scan_bsums<<<1, 256, 0, stream>>>(bsum);
    block_scan<<<NBLK, 256, 0, stream>>>(cnt, bsum, rowptr);
    fill_csr<<<(N_EDGES + 255) / 256, 256, 0, stream>>>(src, dst, rowptr, cursor, col);

    cast_f32_bf16<<<(N_NODES * CH / 4 + 255) / 256, 256, 0, stream>>>(x, xb, N_NODES * CH / 4);
    transpose_w<<<CH, CH, 0, stream>>>(W1, wt1);
    transpose_w<<<CH, CH, 0, stream>>>(W2, wt2);

    dim3 ggrid((N_NODES + BM - 1) / BM, CH / BN);
    gemm_bf16<<<ggrid, 256, 0, stream>>>(xb, wt1, dinv, bufA);
    agg_ln_bf16<<<(N_NODES + 3) / 4, 256, 0, stream>>>(bufA, rowptr, col, dinv, b1, ln1w, ln1b, bufB);
    gemm_bf16<<<ggrid, 256, 0, stream>>>(bufB, wt2, dinv, bufA);
    agg_ln_bf16<<<(N_NODES + 3) / 4, 256, 0, stream>>>(bufA, rowptr, col, dinv, b2, ln2w, ln2b, bufB);
    pool_mean_bf16<<<NUM_GRAPHS, 256, 0, stream>>>(bufB, batch, (float*)d_out);
}